// Round 2
// baseline (381.099 us; speedup 1.0000x reference)
//
#include <hip/hip_runtime.h>

// 192^3 FDTD, float4-vectorized along k (4 elems/thread).
// step1: H2 = H - (DT/mu) * curl(E);  step2: E2 = coefE*E + coefC*curl(H2).
// Central differences defined only on the strict interior of ALL three dims.

#define NXD 192
#define NYD 192
#define NZD 192

static constexpr int   N3    = NXD * NYD * NZD;   // 7,077,888
static constexpr float DTc   = 1e-12f;
static constexpr float INV2D = 500.0f;            // 1/(2*1e-3)

static constexpr int SX = NYD * NZD;  // x stride (36864)
static constexpr int SY = NZD;        // y stride (192)

static constexpr int NQ     = N3 / 4;       // 1,769,472 quads
static constexpr int BLOCK  = 256;
static constexpr int GRID   = NQ / BLOCK;   // 6912 exactly

__device__ __forceinline__ float4 ld4(const float* p) {
    return *reinterpret_cast<const float4*>(p);
}
__device__ __forceinline__ void st4(float* p, float4 v) {
    *reinterpret_cast<float4*>(p) = v;
}
// raw central difference (f[+s] - f[-s]) for aligned strides (s mult of 4)
__device__ __forceinline__ float4 adiff(const float* f, int idx, int s) {
    float4 a = ld4(f + idx + s);
    float4 b = ld4(f + idx - s);
    return make_float4(a.x - b.x, a.y - b.y, a.z - b.z, a.w - b.w);
}
// raw central difference along k for the quad [c..c+3] (c multiple of 4).
// Edge scalars are predicated; out-of-range lanes are masked by caller.
__device__ __forceinline__ float4 zdiff(const float* f, int idx, int c) {
    float4 v = ld4(f + idx);
    float sm = (c > 0)       ? f[idx - 1] : 0.0f;
    float sp = (c < NZD - 4) ? f[idx + 4] : 0.0f;
    return make_float4(v.y - sm, v.z - v.x, v.w - v.y, sp - v.z);
}

__global__ __launch_bounds__(BLOCK) void fdtd_step1(
    const float* __restrict__ Ex, const float* __restrict__ Ey, const float* __restrict__ Ez,
    const float* __restrict__ Hx, const float* __restrict__ Hy, const float* __restrict__ Hz,
    const float* __restrict__ mu,
    float* __restrict__ Hx2, float* __restrict__ Hy2, float* __restrict__ Hz2)
{
    unsigned q = blockIdx.x * BLOCK + threadIdx.x;
    int idx = (int)(q << 2);
    int c = idx % NZD;          // k base of the quad
    unsigned t = idx / NZD;
    int j = (int)(t % NYD);
    int i = (int)(t / NYD);

    float4 cx = make_float4(0.f, 0.f, 0.f, 0.f);
    float4 cy = cx, cz = cx;

    if (i > 0 && i < NXD - 1 && j > 0 && j < NYD - 1) {
        float4 dEzdy = adiff(Ez, idx, SY);
        float4 dEydz = zdiff(Ey, idx, c);
        float4 dExdz = zdiff(Ex, idx, c);
        float4 dEzdx = adiff(Ez, idx, SX);
        float4 dEydx = adiff(Ey, idx, SX);
        float4 dExdy = adiff(Ex, idx, SY);

        cx = make_float4((dEzdy.x - dEydz.x) * INV2D, (dEzdy.y - dEydz.y) * INV2D,
                         (dEzdy.z - dEydz.z) * INV2D, (dEzdy.w - dEydz.w) * INV2D);
        cy = make_float4((dExdz.x - dEzdx.x) * INV2D, (dExdz.y - dEzdx.y) * INV2D,
                         (dExdz.z - dEzdx.z) * INV2D, (dExdz.w - dEzdx.w) * INV2D);
        cz = make_float4((dEydx.x - dExdy.x) * INV2D, (dEydx.y - dExdy.y) * INV2D,
                         (dEydx.z - dExdy.z) * INV2D, (dEydx.w - dExdy.w) * INV2D);

        if (c == 0)       { cx.x = 0.f; cy.x = 0.f; cz.x = 0.f; }   // k == 0
        if (c == NZD - 4) { cx.w = 0.f; cy.w = 0.f; cz.w = 0.f; }   // k == 191
    }

    float4 m  = ld4(mu + idx);
    float4 f  = make_float4(DTc / m.x, DTc / m.y, DTc / m.z, DTc / m.w);
    float4 hx = ld4(Hx + idx), hy = ld4(Hy + idx), hz = ld4(Hz + idx);

    st4(Hx2 + idx, make_float4(hx.x - f.x * cx.x, hx.y - f.y * cx.y,
                               hx.z - f.z * cx.z, hx.w - f.w * cx.w));
    st4(Hy2 + idx, make_float4(hy.x - f.x * cy.x, hy.y - f.y * cy.y,
                               hy.z - f.z * cy.z, hy.w - f.w * cy.w));
    st4(Hz2 + idx, make_float4(hz.x - f.x * cz.x, hz.y - f.y * cz.y,
                               hz.z - f.z * cz.z, hz.w - f.w * cz.w));
}

__global__ __launch_bounds__(BLOCK) void fdtd_step2(
    const float* __restrict__ Ex, const float* __restrict__ Ey, const float* __restrict__ Ez,
    const float* __restrict__ Hx2, const float* __restrict__ Hy2, const float* __restrict__ Hz2,
    const float* __restrict__ eps, const float* __restrict__ sigma,
    float* __restrict__ Ex2, float* __restrict__ Ey2, float* __restrict__ Ez2)
{
    unsigned q = blockIdx.x * BLOCK + threadIdx.x;
    int idx = (int)(q << 2);
    int c = idx % NZD;
    unsigned t = idx / NZD;
    int j = (int)(t % NYD);
    int i = (int)(t / NYD);

    float4 cx = make_float4(0.f, 0.f, 0.f, 0.f);
    float4 cy = cx, cz = cx;

    if (i > 0 && i < NXD - 1 && j > 0 && j < NYD - 1) {
        float4 dHzdy = adiff(Hz2, idx, SY);
        float4 dHydz = zdiff(Hy2, idx, c);
        float4 dHxdz = zdiff(Hx2, idx, c);
        float4 dHzdx = adiff(Hz2, idx, SX);
        float4 dHydx = adiff(Hy2, idx, SX);
        float4 dHxdy = adiff(Hx2, idx, SY);

        cx = make_float4((dHzdy.x - dHydz.x) * INV2D, (dHzdy.y - dHydz.y) * INV2D,
                         (dHzdy.z - dHydz.z) * INV2D, (dHzdy.w - dHydz.w) * INV2D);
        cy = make_float4((dHxdz.x - dHzdx.x) * INV2D, (dHxdz.y - dHzdx.y) * INV2D,
                         (dHxdz.z - dHzdx.z) * INV2D, (dHxdz.w - dHzdx.w) * INV2D);
        cz = make_float4((dHydx.x - dHxdy.x) * INV2D, (dHydx.y - dHxdy.y) * INV2D,
                         (dHydx.z - dHxdy.z) * INV2D, (dHydx.w - dHxdy.w) * INV2D);

        if (c == 0)       { cx.x = 0.f; cy.x = 0.f; cz.x = 0.f; }
        if (c == NZD - 4) { cx.w = 0.f; cy.w = 0.f; cz.w = 0.f; }
    }

    float4 e = ld4(eps + idx);
    float4 s = ld4(sigma + idx);

    float4 coefE, coefC;
    {
        float hs, Ap, r;
        hs = s.x * DTc / (2.f * e.x); Ap = 1.f + hs; r = 1.f / Ap;
        coefE.x = (1.f - hs) * r; coefC.x = DTc * r / e.x;
        hs = s.y * DTc / (2.f * e.y); Ap = 1.f + hs; r = 1.f / Ap;
        coefE.y = (1.f - hs) * r; coefC.y = DTc * r / e.y;
        hs = s.z * DTc / (2.f * e.z); Ap = 1.f + hs; r = 1.f / Ap;
        coefE.z = (1.f - hs) * r; coefC.z = DTc * r / e.z;
        hs = s.w * DTc / (2.f * e.w); Ap = 1.f + hs; r = 1.f / Ap;
        coefE.w = (1.f - hs) * r; coefC.w = DTc * r / e.w;
    }

    float4 ex = ld4(Ex + idx), ey = ld4(Ey + idx), ez = ld4(Ez + idx);

    st4(Ex2 + idx, make_float4(coefE.x * ex.x + coefC.x * cx.x,
                               coefE.y * ex.y + coefC.y * cx.y,
                               coefE.z * ex.z + coefC.z * cx.z,
                               coefE.w * ex.w + coefC.w * cx.w));
    st4(Ey2 + idx, make_float4(coefE.x * ey.x + coefC.x * cy.x,
                               coefE.y * ey.y + coefC.y * cy.y,
                               coefE.z * ey.z + coefC.z * cy.z,
                               coefE.w * ey.w + coefC.w * cy.w));
    st4(Ez2 + idx, make_float4(coefE.x * ez.x + coefC.x * cz.x,
                               coefE.y * ez.y + coefC.y * cz.y,
                               coefE.z * ez.z + coefC.z * cz.z,
                               coefE.w * ez.w + coefC.w * cz.w));
}

extern "C" void kernel_launch(void* const* d_in, const int* in_sizes, int n_in,
                              void* d_out, int out_size, void* d_ws, size_t ws_size,
                              hipStream_t stream)
{
    // setup_inputs order: Ex, Ey, Ez, Hx, Hy, Hz, eps, mu, sigma
    const float* Ex    = (const float*)d_in[0];
    const float* Ey    = (const float*)d_in[1];
    const float* Ez    = (const float*)d_in[2];
    const float* Hx    = (const float*)d_in[3];
    const float* Hy    = (const float*)d_in[4];
    const float* Hz    = (const float*)d_in[5];
    const float* eps   = (const float*)d_in[6];
    const float* mu    = (const float*)d_in[7];
    const float* sigma = (const float*)d_in[8];

    // outputs concatenated: ex2, ey2, ez2, hx2, hy2, hz2
    float* out = (float*)d_out;
    float* Ex2 = out + 0 * (size_t)N3;
    float* Ey2 = out + 1 * (size_t)N3;
    float* Ez2 = out + 2 * (size_t)N3;
    float* Hx2 = out + 3 * (size_t)N3;
    float* Hy2 = out + 4 * (size_t)N3;
    float* Hz2 = out + 5 * (size_t)N3;

    fdtd_step1<<<GRID, BLOCK, 0, stream>>>(Ex, Ey, Ez, Hx, Hy, Hz, mu, Hx2, Hy2, Hz2);
    fdtd_step2<<<GRID, BLOCK, 0, stream>>>(Ex, Ey, Ez, Hx2, Hy2, Hz2, eps, sigma, Ex2, Ey2, Ez2);
}